// Round 4
// baseline (359.632 us; speedup 1.0000x reference)
//
#include <hip/hip_runtime.h>
#include <hip/hip_bf16.h>

#define IMG_H 512
#define IMG_W 512
#define PAD   256      // max_size = GS * 2^(N_GLIMPSES-1)
#define HP    1024     // padded height/width
#define BATCH 64
#define KTOT  36864    // 64*64*9 contraction length
#define KTILE 192      // K per GEMM block
#define NTILES 192     // KTOT / KTILE -> 192 blocks, 1 per CU

typedef __attribute__((ext_vector_type(8))) short short8;
typedef __attribute__((ext_vector_type(4))) float f32x4;

// ---- compile-time Keys cubic (a=-0.5) antialias weights -------------------
constexpr float keysc(float a) {
  return a >= 2.0f ? 0.0f
       : a >= 1.0f ? ((-0.5f * a + 2.5f) * a - 4.0f) * a + 2.0f
       : (1.5f * a - 2.5f) * a * a + 1.0f;
}
constexpr float fabsc(float x) { return x < 0.f ? -x : x; }
// scale2 (KS=4): sample offset |7.5 - t|/4, t=0..15 ; scale1 (KS=2): |3.5 - t|/2, t=0..7
constexpr float K2c(int t) { return keysc(fabsc(7.5f - (float)t) * 0.25f); }
constexpr float K1c(int t) { return keysc(fabsc(3.5f - (float)t) * 0.5f); }
constexpr float C2 = K2c(0)+K2c(1)+K2c(2)+K2c(3)+K2c(4)+K2c(5)+K2c(6)+K2c(7)
                    +K2c(8)+K2c(9)+K2c(10)+K2c(11)+K2c(12)+K2c(13)+K2c(14)+K2c(15);
constexpr float C1 = K1c(0)+K1c(1)+K1c(2)+K1c(3)+K1c(4)+K1c(5)+K1c(6)+K1c(7);
__device__ constexpr float KN2[16] = {
  K2c(0)/C2, K2c(1)/C2, K2c(2)/C2, K2c(3)/C2, K2c(4)/C2, K2c(5)/C2, K2c(6)/C2, K2c(7)/C2,
  K2c(8)/C2, K2c(9)/C2, K2c(10)/C2, K2c(11)/C2, K2c(12)/C2, K2c(13)/C2, K2c(14)/C2, K2c(15)/C2};
__device__ constexpr float KN1[8] = {
  K1c(0)/C1, K1c(1)/C1, K1c(2)/C1, K1c(3)/C1, K1c(4)/C1, K1c(5)/C1, K1c(6)/C1, K1c(7)/C1};

// reciprocal of in-crop weight sum for out-index o (interior == 1)
__device__ __forceinline__ float enorm2(int o) {  // crop size 256, i0 = 4o-6
  if (o >= 2 && o <= 61) return 1.0f;
  float s = 0.f;
#pragma unroll
  for (int t = 0; t < 16; ++t) { int i = 4 * o - 6 + t; if ((unsigned)i < 256u) s += KN2[t]; }
  return 1.0f / s;
}
__device__ __forceinline__ float enorm1(int o) {  // crop size 128, i0 = 2o-3
  if (o >= 2 && o <= 61) return 1.0f;
  float s = 0.f;
#pragma unroll
  for (int t = 0; t < 8; ++t) { int i = 2 * o - 3 + t; if ((unsigned)i < 128u) s += KN1[t]; }
  return 1.0f / s;
}

__device__ __forceinline__ int iclamp(int v, int lo, int hi) { return min(max(v, lo), hi); }
__device__ __forceinline__ unsigned short f2bits(float f) {
  __hip_bfloat16 h = __float2bfloat16(f);
  unsigned short s;
  __builtin_memcpy(&s, &h, 2);
  return s;
}

// ---------------------------------------------------------------------------
// Glimpse kernel: grid = BATCH * 12 blocks. Per b: 4 scale2 + 4 scale1 +
// 4 scale0 blocks, each covering 16 output rows. Source rows are streamed:
// each is read ONCE from global; register accumulators (col x 16 out-rows).
// G output layout: [b][y][x][ch0..8] bf16 (bits in ushort).
// ---------------------------------------------------------------------------
__global__ __launch_bounds__(256) void glimpse_kernel(
    const float* __restrict__ img, const float* __restrict__ loc,
    unsigned short* __restrict__ G) {
  __shared__ __align__(16) float smem[16 * 768 + 16];  // tmp (48KB) + vnorm[16]
  float* tmp = smem;
  float* vn  = smem + 16 * 768;

  const int blk = blockIdx.x;
  const int b   = blk / 12;
  const int r12 = blk - 12 * b;
  const int tid = threadIdx.x;

  const float cy = (loc[2 * b] + 1.0f) * 0.5f * 1024.0f;
  const float cx = (loc[2 * b + 1] + 1.0f) * 0.5f * 1024.0f;
  const float* imb = img + (size_t)b * (IMG_H * IMG_W * 3);

  if (r12 >= 8) {  // ---- scale 0: identity crop copy, 16 rows ----
    const int y0 = 16 * (r12 - 8);
    const int tly0 = iclamp((int)rintf(cy - 32.0f), 0, HP - 64);
    const int tlx0 = iclamp((int)rintf(cx - 32.0f), 0, HP - 64);
#pragma unroll
    for (int p = 0; p < 12; ++p) {
      int oi = tid + 256 * p;  // 0..3071
      int yl = oi / 192, rem = oi - 192 * yl, x = rem / 3, c = rem - 3 * x;
      int py = tly0 + y0 + yl - PAD, px = tlx0 + x - PAD;
      float v = 0.0f;
      if ((unsigned)py < (unsigned)IMG_H && (unsigned)px < (unsigned)IMG_W)
        v = imb[(py * IMG_W + px) * 3 + c];
      G[(((size_t)b * 64 + y0 + yl) * 64 + x) * 9 + c] = f2bits(v);
    }
    return;
  }

  if (r12 < 4) {  // ---- scale 2 (KS=4, crop 256): 16 out-rows ----
    const int y0 = 16 * r12;
    const int tly = iclamp((int)rintf(cy - 128.0f), 0, HP - 256);
    const int tlx = iclamp((int)rintf(cx - 128.0f), 0, HP - 256);
    // thread owns 3 columns e, e+256, e+512 (e = tid), all 16 out-rows
    const int cb = (tlx - PAD) * 3;
    const int xA = tid / 3, xB = (tid + 256) / 3, xC = (tid + 512) / 3;
    const bool mA = (unsigned)(tlx - PAD + xA) < (unsigned)IMG_W;
    const bool mB = (unsigned)(tlx - PAD + xB) < (unsigned)IMG_W;
    const bool mC = (unsigned)(tlx - PAD + xC) < (unsigned)IMG_W;
    float a0[16], a1[16], a2[16];
#pragma unroll
    for (int i = 0; i < 16; ++i) { a0[i] = 0.f; a1[i] = 0.f; a2[i] = 0.f; }
    const int rbase = 4 * y0 - 6;
#pragma unroll
    for (int k = 0; k < 76; ++k) {
      const int r = rbase + k;          // crop row
      const int py = tly - PAD + r;     // image row
      if ((unsigned)r < 256u && (unsigned)py < (unsigned)IMG_H) {
        const float* rp = imb + (size_t)py * (IMG_W * 3) + cb;
        float v0 = mA ? rp[tid] : 0.f;
        float v1 = mB ? rp[tid + 256] : 0.f;
        float v2 = mC ? rp[tid + 512] : 0.f;
#pragma unroll
        for (int d = 0; d < 4; ++d) {
          const int yl = (k >> 2) - d;        // static
          const int t  = (k & 3) + 4 * d;     // static, in [0,16)
          if (yl >= 0 && yl < 16) {
            const float w = KN2[t];           // compile-time constant
            a0[yl] = fmaf(w, v0, a0[yl]);
            a1[yl] = fmaf(w, v1, a1[yl]);
            a2[yl] = fmaf(w, v2, a2[yl]);
          }
        }
      }
    }
#pragma unroll
    for (int yl = 0; yl < 16; ++yl) {
      tmp[yl * 768 + tid]       = a0[yl];
      tmp[yl * 768 + tid + 256] = a1[yl];
      tmp[yl * 768 + tid + 512] = a2[yl];
    }
    if (tid < 16) vn[tid] = enorm2(y0 + tid);
    __syncthreads();
    // horizontal: 16 rows x 64 xo x 3 ch
#pragma unroll
    for (int p = 0; p < 12; ++p) {
      int oi = tid + 256 * p;
      int yl = oi / 192, rem = oi - 192 * yl, xo = rem / 3, c = rem - 3 * xo;
      const float* trow = tmp + yl * 768 + c;
      const int i0 = 4 * xo - 6;
      float a = 0.f;
      if (xo >= 2 && xo <= 61) {
#pragma unroll
        for (int t = 0; t < 16; ++t) a = fmaf(KN2[t], trow[(i0 + t) * 3], a);
      } else {
#pragma unroll
        for (int t = 0; t < 16; ++t) {
          int i = i0 + t;
          if ((unsigned)i < 256u) a = fmaf(KN2[t], trow[i * 3], a);
        }
      }
      a *= enorm2(xo) * vn[yl];
      G[(((size_t)b * 64 + y0 + yl) * 64 + xo) * 9 + 6 + c] = f2bits(a);
    }
    return;
  }

  // ---- scale 1 (KS=2, crop 128): 16 out-rows ----
  {
    const int y0 = 16 * (r12 - 4);
    const int tly = iclamp((int)rintf(cy - 64.0f), 0, HP - 128);
    const int tlx = iclamp((int)rintf(cx - 64.0f), 0, HP - 128);
    const int cb = (tlx - PAD) * 3;
    // threads 0..191 own 2 cols each (e = 2*tid, 2*tid+1)
    float a0[16], a1[16];
#pragma unroll
    for (int i = 0; i < 16; ++i) { a0[i] = 0.f; a1[i] = 0.f; }
    const int e0 = 2 * tid, e1 = 2 * tid + 1;
    const bool act = tid < 192;
    const bool mA = act && ((unsigned)(tlx - PAD + e0 / 3) < (unsigned)IMG_W);
    const bool mB = act && ((unsigned)(tlx - PAD + e1 / 3) < (unsigned)IMG_W);
    const int rbase = 2 * y0 - 3;
#pragma unroll
    for (int k = 0; k < 38; ++k) {
      const int r = rbase + k;
      const int py = tly - PAD + r;
      if ((unsigned)r < 128u && (unsigned)py < (unsigned)IMG_H) {
        const float* rp = imb + (size_t)py * (IMG_W * 3) + cb;
        float v0 = mA ? rp[e0] : 0.f;
        float v1 = mB ? rp[e1] : 0.f;
#pragma unroll
        for (int d = 0; d < 4; ++d) {
          const int yl = (k >> 1) - d;
          const int t  = (k & 1) + 2 * d;   // in [0,8)
          if (yl >= 0 && yl < 16) {
            const float w = KN1[t];
            a0[yl] = fmaf(w, v0, a0[yl]);
            a1[yl] = fmaf(w, v1, a1[yl]);
          }
        }
      }
    }
    if (act) {
#pragma unroll
      for (int yl = 0; yl < 16; ++yl) {
        tmp[yl * 384 + e0] = a0[yl];
        tmp[yl * 384 + e1] = a1[yl];
      }
    }
    if (tid < 16) vn[tid] = enorm1(y0 + tid);
    __syncthreads();
#pragma unroll
    for (int p = 0; p < 12; ++p) {
      int oi = tid + 256 * p;
      int yl = oi / 192, rem = oi - 192 * yl, xo = rem / 3, c = rem - 3 * xo;
      const float* trow = tmp + yl * 384 + c;
      const int i0 = 2 * xo - 3;
      float a = 0.f;
      if (xo >= 2 && xo <= 61) {
#pragma unroll
        for (int t = 0; t < 8; ++t) a = fmaf(KN1[t], trow[(i0 + t) * 3], a);
      } else {
#pragma unroll
        for (int t = 0; t < 8; ++t) {
          int i = i0 + t;
          if ((unsigned)i < 128u) a = fmaf(KN1[t], trow[i * 3], a);
        }
      }
      a *= enorm1(xo) * vn[yl];
      G[(((size_t)b * 64 + y0 + yl) * 64 + xo) * 9 + 3 + c] = f2bits(a);
    }
  }
}

// ---------------------------------------------------------------------------
// Split-K MFMA GEMM: partial[m][tile][n] = G[64, KTILE] @ Wg[KTILE, 128]
// grid: 192 blocks x 256 thr (4 waves). G-slice staged to LDS once (one
// barrier total); B loaded straight from global (each Wg element read once),
// converted to bf16 in-reg. MFMA 16x16x32 bf16: wave w owns n in [32w,32w+32).
// ---------------------------------------------------------------------------
__global__ __launch_bounds__(256) void gemm_kernel(
    const unsigned short* __restrict__ G, const float* __restrict__ Wg,
    float* __restrict__ partials) {
  __shared__ __align__(16) unsigned short Gs[64 * 200];  // rows padded 192->200
  const int tid  = threadIdx.x;
  const int tile = blockIdx.x;
  const int kt   = tile * KTILE;

  {  // stage G tile: 64 rows x 192 bf16 (384 B/row), 16B chunks
    const int m = tid >> 2, i = tid & 3;
    const unsigned short* src = G + (size_t)m * KTOT + kt;
    unsigned short* dst = Gs + m * 200;
#pragma unroll
    for (int p = 0; p < 6; ++p) {
      const int o8 = (i + 4 * p) * 8;
      *(float4*)(dst + o8) = *(const float4*)(src + o8);
    }
  }
  __syncthreads();

  const int lane = tid & 63;
  const int wv   = tid >> 6;
  const int ln   = lane & 15;
  const int q    = lane >> 4;
  const int nb   = wv * 32 + ln;

  f32x4 acc[4][2];
#pragma unroll
  for (int mt = 0; mt < 4; ++mt)
#pragma unroll
    for (int nt = 0; nt < 2; ++nt) {
      acc[mt][nt][0] = 0.f; acc[mt][nt][1] = 0.f;
      acc[mt][nt][2] = 0.f; acc[mt][nt][3] = 0.f;
    }

#pragma unroll
  for (int s = 0; s < 6; ++s) {
    short8 af[4];
#pragma unroll
    for (int mt = 0; mt < 4; ++mt)
      af[mt] = *(const short8*)(Gs + (mt * 16 + ln) * 200 + s * 32 + q * 8);
    short8 bf[2];
#pragma unroll
    for (int nt = 0; nt < 2; ++nt) {
      const float* wp = Wg + (size_t)(kt + s * 32 + q * 8) * 128 + nb + nt * 16;
      short8 v;
#pragma unroll
      for (int j = 0; j < 8; ++j) v[j] = (short)f2bits(wp[j * 128]);
      bf[nt] = v;
    }
#pragma unroll
    for (int mt = 0; mt < 4; ++mt)
#pragma unroll
      for (int nt = 0; nt < 2; ++nt)
        acc[mt][nt] = __builtin_amdgcn_mfma_f32_16x16x32_bf16(
            af[mt], bf[nt], acc[mt][nt], 0, 0, 0);
  }

  // C layout: col = lane&15 (+16*nt +32*wv), row = (lane>>4)*4 + i (+16*mt)
#pragma unroll
  for (int mt = 0; mt < 4; ++mt)
#pragma unroll
    for (int nt = 0; nt < 2; ++nt)
#pragma unroll
      for (int i = 0; i < 4; ++i) {
        const int row = mt * 16 + q * 4 + i;
        const int col = nb + nt * 16;
        partials[((size_t)row * NTILES + tile) * 128 + col] = acc[mt][nt][i];
      }
}

// ---------------------------------------------------------------------------
// Reduce split-K partials, add biases, fuse loc branch and output layer.
// grid: 64 blocks x 256 thr. Contiguous 96 KB slab per b, float4 streaming.
// ---------------------------------------------------------------------------
__global__ __launch_bounds__(256) void finalize_kernel(
    const float* __restrict__ partials, const float* __restrict__ loc,
    const float* __restrict__ bg, const float* __restrict__ Wl,
    const float* __restrict__ bl, const float* __restrict__ Wo,
    const float* __restrict__ bo, float* __restrict__ out) {
  const int b   = blockIdx.x;
  const int tid = threadIdx.x;

  const float4* base = (const float4*)(partials + (size_t)b * NTILES * 128);
  float4 acc = make_float4(0.f, 0.f, 0.f, 0.f);
  // NTILES*128 = 24576 floats = 6144 float4; k = (tid&31)*4 + j
#pragma unroll 6
  for (int i = 0; i < 24; ++i) {
    float4 v = base[(size_t)i * 256 + tid];
    acc.x += v.x; acc.y += v.y; acc.z += v.z; acc.w += v.w;
  }

  __shared__ float red[8][128];
  __shared__ float h[128];
  {
    float* r = &red[tid >> 5][(tid & 31) * 4];
    r[0] = acc.x; r[1] = acc.y; r[2] = acc.z; r[3] = acc.w;
  }
  __syncthreads();
  if (tid < 128) {
    float ss = 0.0f;
#pragma unroll
    for (int g = 0; g < 8; ++g) ss += red[g][tid];
    float x1 = fmaxf(ss + bg[tid], 0.0f);
    float x2 = fmaxf(fmaf(loc[2 * b], Wl[tid],
                          fmaf(loc[2 * b + 1], Wl[128 + tid], bl[tid])),
                     0.0f);
    h[tid] = x1 + x2;
  }
  __syncthreads();
  {
    const int n = tid;
    float a = bo[n];
#pragma unroll 8
    for (int kk = 0; kk < 128; ++kk) a = fmaf(h[kk], Wo[kk * 256 + n], a);
    out[(size_t)b * 256 + n] = fmaxf(a, 0.0f);
  }
}

extern "C" void kernel_launch(void* const* d_in, const int* in_sizes, int n_in,
                              void* d_out, int out_size, void* d_ws, size_t ws_size,
                              hipStream_t stream) {
  const float* img = (const float*)d_in[0];
  const float* loc = (const float*)d_in[1];
  const float* Wg  = (const float*)d_in[2];
  const float* bg  = (const float*)d_in[3];
  const float* Wl  = (const float*)d_in[4];
  const float* bl  = (const float*)d_in[5];
  const float* Wo  = (const float*)d_in[6];
  const float* bo  = (const float*)d_in[7];
  float* out = (float*)d_out;

  char* ws = (char*)d_ws;
  unsigned short* G = (unsigned short*)ws;              // 2359296 bf16 = 4.72 MB
  float* partials   = (float*)(ws + 2359296 * 2);       // 64*192*128 f32 = 6.3 MB

  glimpse_kernel<<<BATCH * 12, 256, 0, stream>>>(img, loc, G);
  gemm_kernel<<<NTILES, 256, 0, stream>>>(G, Wg, partials);
  finalize_kernel<<<BATCH, 256, 0, stream>>>(partials, loc, bg, Wl, bl, Wo, bo, out);
}

// Round 5
// 315.121 us; speedup vs baseline: 1.1412x; 1.1412x over previous
//
#include <hip/hip_runtime.h>
#include <hip/hip_bf16.h>

#define IMG_H 512
#define IMG_W 512
#define PAD   256      // max_size = GS * 2^(N_GLIMPSES-1)
#define HP    1024     // padded height/width
#define BATCH 64
#define KTOT  36864    // 64*64*9 contraction length
#define KTILE 96       // K per GEMM block (3 MFMA k-steps of 32)
#define NTILES 384     // KTOT / KTILE -> 1.5 blocks/CU
#define GSTRIDE 104    // LDS row stride in ushorts (208 B, 16B-aligned)

typedef __attribute__((ext_vector_type(8))) short short8;
typedef __attribute__((ext_vector_type(4))) float f32x4;

// Keys cubic kernel, a = -0.5 (matches jax.image resize 'cubic')
__device__ __forceinline__ float keys_cubic(float x) {
  if (x >= 2.0f) return 0.0f;
  if (x >= 1.0f) return ((-0.5f * x + 2.5f) * x - 4.0f) * x + 2.0f;
  return ((1.5f * x - 2.5f) * x) * x + 1.0f;
}

__device__ __forceinline__ int iclamp(int v, int lo, int hi) {
  return min(max(v, lo), hi);
}
__device__ __forceinline__ unsigned short f2bits(float f) {
  __hip_bfloat16 h = __float2bfloat16(f);
  unsigned short s;
  __builtin_memcpy(&s, &h, 2);
  return s;
}

// One block per (b, y): computes all 3 scales of output row y for batch b.
// grid: BATCH * 64 = 4096 blocks, 256 threads. (Exact R3 structure; G in bf16.)
__global__ __launch_bounds__(256) void glimpse_kernel(
    const float* __restrict__ img, const float* __restrict__ loc,
    unsigned short* __restrict__ G) {
  __shared__ float tmp1[384];  // sc=1 vertical result: S=128 cols x 3 ch
  __shared__ float tmp2[768];  // sc=2 vertical result: S=256 cols x 3 ch
  const int y   = blockIdx.x & 63;
  const int b   = blockIdx.x >> 6;
  const int tid = threadIdx.x;

  // center / top-left: bit-identical to reference fp32 math, banker's rounding
  const float cy = (loc[2 * b] + 1.0f) * 0.5f * 1024.0f;
  const float cx = (loc[2 * b + 1] + 1.0f) * 0.5f * 1024.0f;
  const int tly0 = iclamp((int)rintf(cy - 32.0f), 0, HP - 64);
  const int tlx0 = iclamp((int)rintf(cx - 32.0f), 0, HP - 64);
  const int tly1 = iclamp((int)rintf(cy - 64.0f), 0, HP - 128);
  const int tlx1 = iclamp((int)rintf(cx - 64.0f), 0, HP - 128);
  const int tly2 = iclamp((int)rintf(cy - 128.0f), 0, HP - 256);
  const int tlx2 = iclamp((int)rintf(cx - 128.0f), 0, HP - 256);
  const float* imb = img + (size_t)b * (IMG_H * IMG_W * 3);
  unsigned short* Grow = G + ((size_t)b * 64 + y) * (64 * 9);

  // ---- scale 0: 64->64 resize is exactly identity: zero-padded crop copy ----
  if (tid < 192) {
    int x = tid / 3, c = tid - 3 * (tid / 3);
    int py = tly0 + y - PAD, px = tlx0 + x - PAD;
    float v = 0.0f;
    if ((unsigned)py < (unsigned)IMG_H && (unsigned)px < (unsigned)IMG_W)
      v = imb[(py * IMG_W + px) * 3 + c];
    Grow[x * 9 + c] = f2bits(v);
  }

  // ---- vertical weights (normalized over in-range taps) ----
  float wy1[8];
  int iy0_1;
  {
    float sy = ((float)y + 0.5f) * 2.0f - 0.5f;
    iy0_1 = (int)ceilf(sy - 4.0f);
    float ws = 0.0f;
#pragma unroll
    for (int t = 0; t < 8; ++t) {
      int i = iy0_1 + t;
      float w = (i >= 0 && i < 128) ? keys_cubic(fabsf(sy - (float)i) * 0.5f) : 0.0f;
      wy1[t] = w;
      ws += w;
    }
    float wi = 1.0f / ws;
#pragma unroll
    for (int t = 0; t < 8; ++t) wy1[t] *= wi;
  }
  float wy2[16];
  int iy0_2;
  {
    float sy = ((float)y + 0.5f) * 4.0f - 0.5f;
    iy0_2 = (int)ceilf(sy - 8.0f);
    float ws = 0.0f;
#pragma unroll
    for (int t = 0; t < 16; ++t) {
      int i = iy0_2 + t;
      float w = (i >= 0 && i < 256) ? keys_cubic(fabsf(sy - (float)i) * 0.25f) : 0.0f;
      wy2[t] = w;
      ws += w;
    }
    float wi = 1.0f / ws;
#pragma unroll
    for (int t = 0; t < 16; ++t) wy2[t] *= wi;
  }

  // ---- vertical pass, scale 1: 384 elements ----
  for (int e = tid; e < 384; e += 256) {
    int x = e / 3, c = e - 3 * (e / 3);
    int px = tlx1 - PAD + x;
    float a = 0.0f;
    if ((unsigned)px < (unsigned)IMG_W) {
      const float* colp = imb + (px * 3 + c);
#pragma unroll
      for (int t = 0; t < 8; ++t) {
        int py = tly1 + iy0_1 + t - PAD;
        if ((unsigned)py < (unsigned)IMG_H)
          a = fmaf(wy1[t], colp[py * (IMG_W * 3)], a);
      }
    }
    tmp1[e] = a;
  }
  // ---- vertical pass, scale 2: 768 elements ----
  for (int e = tid; e < 768; e += 256) {
    int x = e / 3, c = e - 3 * (e / 3);
    int px = tlx2 - PAD + x;
    float a = 0.0f;
    if ((unsigned)px < (unsigned)IMG_W) {
      const float* colp = imb + (px * 3 + c);
#pragma unroll
      for (int t = 0; t < 16; ++t) {
        int py = tly2 + iy0_2 + t - PAD;
        if ((unsigned)py < (unsigned)IMG_H)
          a = fmaf(wy2[t], colp[py * (IMG_W * 3)], a);
      }
    }
    tmp2[e] = a;
  }
  __syncthreads();

  // ---- horizontal pass, both scales: 384 outputs, wave-uniform branches ----
  for (int o = tid; o < 384; o += 256) {
    int oo = (o >= 192) ? o - 192 : o;
    int xo = oo / 3, c = oo - 3 * xo;
    if (o < 192) {  // scale 1 (KS=2)
      float sx  = ((float)xo + 0.5f) * 2.0f - 0.5f;
      int   ix0 = (int)ceilf(sx - 4.0f);
      float a = 0.0f, wsx = 0.0f;
#pragma unroll
      for (int t = 0; t < 8; ++t) {
        int i = ix0 + t;
        if (i >= 0 && i < 128) {
          float w = keys_cubic(fabsf(sx - (float)i) * 0.5f);
          wsx += w;
          a = fmaf(w, tmp1[i * 3 + c], a);
        }
      }
      Grow[xo * 9 + 3 + c] = f2bits(a / wsx);
    } else {        // scale 2 (KS=4)
      float sx  = ((float)xo + 0.5f) * 4.0f - 0.5f;
      int   ix0 = (int)ceilf(sx - 8.0f);
      float a = 0.0f, wsx = 0.0f;
#pragma unroll
      for (int t = 0; t < 16; ++t) {
        int i = ix0 + t;
        if (i >= 0 && i < 256) {
          float w = keys_cubic(fabsf(sx - (float)i) * 0.25f);
          wsx += w;
          a = fmaf(w, tmp2[i * 3 + c], a);
        }
      }
      Grow[xo * 9 + 6 + c] = f2bits(a / wsx);
    }
  }
}

// ---------------------------------------------------------------------------
// Split-K MFMA GEMM: partial[m][tile][n] = G[64, KTILE] @ Wg[KTILE, 128]
// grid: 384 blocks x 256 thr (4 waves, 1.5 blocks/CU). G-slice staged to LDS
// once (single barrier); B loaded straight from global (each Wg element read
// once per tile, lane-coalesced), converted to bf16 in-reg.
// MFMA 16x16x32 bf16; wave wv owns n in [32wv, 32wv+32).
// ---------------------------------------------------------------------------
__global__ __launch_bounds__(256) void gemm_kernel(
    const unsigned short* __restrict__ G, const float* __restrict__ Wg,
    float* __restrict__ partials) {
  __shared__ __align__(16) unsigned short Gs[64 * GSTRIDE];  // 13 KB
  const int tid  = threadIdx.x;
  const int tile = blockIdx.x;
  const int kt   = tile * KTILE;

  {  // stage G tile: 64 rows x 96 bf16 (192 B/row) = 12 float4-chunks/row
    const int m = tid >> 2, i = tid & 3;
    const unsigned short* src = G + (size_t)m * KTOT + kt;
    unsigned short* dst = Gs + m * GSTRIDE;
#pragma unroll
    for (int p = 0; p < 3; ++p) {
      const int o8 = (i + 4 * p) * 8;
      *(float4*)(dst + o8) = *(const float4*)(src + o8);
    }
  }
  __syncthreads();

  const int lane = tid & 63;
  const int wv   = tid >> 6;
  const int ln   = lane & 15;
  const int q    = lane >> 4;
  const int nb   = wv * 32 + ln;

  f32x4 acc[4][2];
#pragma unroll
  for (int mt = 0; mt < 4; ++mt)
#pragma unroll
    for (int nt = 0; nt < 2; ++nt) {
      acc[mt][nt][0] = 0.f; acc[mt][nt][1] = 0.f;
      acc[mt][nt][2] = 0.f; acc[mt][nt][3] = 0.f;
    }

#pragma unroll
  for (int s = 0; s < KTILE / 32; ++s) {  // 3
    short8 af[4];
#pragma unroll
    for (int mt = 0; mt < 4; ++mt)
      af[mt] = *(const short8*)(Gs + (mt * 16 + ln) * GSTRIDE + s * 32 + q * 8);
    short8 bf[2];
#pragma unroll
    for (int nt = 0; nt < 2; ++nt) {
      const float* wp = Wg + (size_t)(kt + s * 32 + q * 8) * 128 + nb + nt * 16;
      short8 v;
#pragma unroll
      for (int j = 0; j < 8; ++j) v[j] = (short)f2bits(wp[j * 128]);
      bf[nt] = v;
    }
#pragma unroll
    for (int mt = 0; mt < 4; ++mt)
#pragma unroll
      for (int nt = 0; nt < 2; ++nt)
        acc[mt][nt] = __builtin_amdgcn_mfma_f32_16x16x32_bf16(
            af[mt], bf[nt], acc[mt][nt], 0, 0, 0);
  }

  // C layout: col = lane&15 (+16*nt +32*wv), row = (lane>>4)*4 + i (+16*mt)
#pragma unroll
  for (int mt = 0; mt < 4; ++mt)
#pragma unroll
    for (int nt = 0; nt < 2; ++nt)
#pragma unroll
      for (int i = 0; i < 4; ++i) {
        const int row = mt * 16 + q * 4 + i;
        const int col = nb + nt * 16;
        partials[((size_t)row * NTILES + tile) * 128 + col] = acc[mt][nt][i];
      }
}

// ---------------------------------------------------------------------------
// Reduce split-K partials, add biases, fuse loc branch and output layer.
// grid: 64 blocks x 256 thr. Contiguous 192 KB slab per b, float4 streaming.
// ---------------------------------------------------------------------------
__global__ __launch_bounds__(256) void finalize_kernel(
    const float* __restrict__ partials, const float* __restrict__ loc,
    const float* __restrict__ bg, const float* __restrict__ Wl,
    const float* __restrict__ bl, const float* __restrict__ Wo,
    const float* __restrict__ bo, float* __restrict__ out) {
  const int b   = blockIdx.x;
  const int tid = threadIdx.x;

  const float4* base = (const float4*)(partials + (size_t)b * NTILES * 128);
  float4 acc = make_float4(0.f, 0.f, 0.f, 0.f);
  // NTILES*128 = 49152 floats = 12288 float4; k = (tid&31)*4 + j
#pragma unroll 8
  for (int i = 0; i < 48; ++i) {
    float4 v = base[(size_t)i * 256 + tid];
    acc.x += v.x; acc.y += v.y; acc.z += v.z; acc.w += v.w;
  }

  __shared__ float red[8][128];
  __shared__ float h[128];
  {
    float* r = &red[tid >> 5][(tid & 31) * 4];
    r[0] = acc.x; r[1] = acc.y; r[2] = acc.z; r[3] = acc.w;
  }
  __syncthreads();
  if (tid < 128) {
    float ss = 0.0f;
#pragma unroll
    for (int g = 0; g < 8; ++g) ss += red[g][tid];
    float x1 = fmaxf(ss + bg[tid], 0.0f);
    float x2 = fmaxf(fmaf(loc[2 * b], Wl[tid],
                          fmaf(loc[2 * b + 1], Wl[128 + tid], bl[tid])),
                     0.0f);
    h[tid] = x1 + x2;
  }
  __syncthreads();
  {
    const int n = tid;
    float a = bo[n];
#pragma unroll 8
    for (int kk = 0; kk < 128; ++kk) a = fmaf(h[kk], Wo[kk * 256 + n], a);
    out[(size_t)b * 256 + n] = fmaxf(a, 0.0f);
  }
}

extern "C" void kernel_launch(void* const* d_in, const int* in_sizes, int n_in,
                              void* d_out, int out_size, void* d_ws, size_t ws_size,
                              hipStream_t stream) {
  const float* img = (const float*)d_in[0];
  const float* loc = (const float*)d_in[1];
  const float* Wg  = (const float*)d_in[2];
  const float* bg  = (const float*)d_in[3];
  const float* Wl  = (const float*)d_in[4];
  const float* bl  = (const float*)d_in[5];
  const float* Wo  = (const float*)d_in[6];
  const float* bo  = (const float*)d_in[7];
  float* out = (float*)d_out;

  char* ws = (char*)d_ws;
  unsigned short* G = (unsigned short*)ws;           // 2359296 bf16 = 4.72 MB
  float* partials   = (float*)(ws + 2359296 * 2);    // 64*384*128 f32 = 12.6 MB

  glimpse_kernel<<<BATCH * 64, 256, 0, stream>>>(img, loc, G);
  gemm_kernel<<<NTILES, 256, 0, stream>>>(G, Wg, partials);
  finalize_kernel<<<BATCH, 256, 0, stream>>>(partials, loc, bg, Wl, bl, Wo, bo, out);
}